// Round 1
// baseline (6616.061 us; speedup 1.0000x reference)
//
#include <hip/hip_runtime.h>
#include <hip/hip_bf16.h>

#define DIMN 256
#define TLEN 256
#define SL_ROWS 128   // rows of S^T cached in LDS (128 KB)

// ---------------- prep kernels: build P^T, S^T, W^T, D^T in ws ----------------
// Layouts (all row-major flat):
//   Pt[j*256+i] = P[i][j],  P = D^T F D
//   St[j*256+i] = S[i][j],  S = I - (1/a) D^T (A^T A + lam2 I) D
//   Wt[d*256+i] = W[i][d],  W = (1/a) D^T A^T A
//   Dt[d*256+n] = D[n][d]

__global__ void prep1(const float* __restrict__ A, const float* __restrict__ D,
                      const float* __restrict__ F, const float* __restrict__ lam2p,
                      float* __restrict__ FD, float* __restrict__ G,
                      float* __restrict__ AD, float* __restrict__ Dt) {
    int gid = blockIdx.x * 256 + threadIdx.x;
    if (gid < 65536) {                   // FD[k][j] = sum_q F[k][q] D[q][j]
        int k = gid >> 8, j = gid & 255;
        float s = 0.f;
        #pragma unroll 8
        for (int q = 0; q < 256; ++q) s += F[k*256+q] * D[q*256+j];
        FD[gid] = s;
    } else if (gid < 131072) {           // G[p][q] = sum_m A[m][p] A[m][q] + lam2*(p==q)
        int g = gid - 65536; int p = g >> 8, q = g & 255;
        float s = (p == q) ? lam2p[0] : 0.f;
        #pragma unroll 8
        for (int m = 0; m < 64; ++m) s += A[m*256+p] * A[m*256+q];
        G[g] = s;
    } else if (gid < 147456) {           // AD[m][i] = sum_k A[m][k] D[k][i]
        int g = gid - 131072; int m = g >> 8, i = g & 255;
        float s = 0.f;
        #pragma unroll 8
        for (int k = 0; k < 256; ++k) s += A[m*256+k] * D[k*256+i];
        AD[g] = s;
    } else if (gid < 212992) {           // Dt[d][n] = D[n][d]
        int g = gid - 147456; int d = g >> 8, n = g & 255;
        Dt[g] = D[n*256+d];
    }
}

__global__ void prep2(const float* __restrict__ A, const float* __restrict__ D,
                      const float* __restrict__ alphap,
                      const float* __restrict__ FD, const float* __restrict__ G,
                      const float* __restrict__ AD,
                      float* __restrict__ Pt, float* __restrict__ GD,
                      float* __restrict__ Wt) {
    int gid = blockIdx.x * 256 + threadIdx.x;
    float inva = 1.0f / alphap[0];
    if (gid < 65536) {                   // Pt[j][i] = sum_k D[k][i] FD[k][j]
        int j = gid >> 8, i = gid & 255;
        float s = 0.f;
        #pragma unroll 8
        for (int k = 0; k < 256; ++k) s += D[k*256+i] * FD[k*256+j];
        Pt[gid] = s;
    } else if (gid < 131072) {           // GD[k][j] = sum_q G[k][q] D[q][j]
        int g = gid - 65536; int k = g >> 8, j = g & 255;
        float s = 0.f;
        #pragma unroll 8
        for (int q = 0; q < 256; ++q) s += G[k*256+q] * D[q*256+j];
        GD[g] = s;
    } else {                             // Wt[d][i] = inva * sum_m AD[m][i] A[m][d]
        int g = gid - 131072; int d = g >> 8, i = g & 255;
        float s = 0.f;
        #pragma unroll 8
        for (int m = 0; m < 64; ++m) s += AD[m*256+i] * A[m*256+d];
        Wt[g] = inva * s;
    }
}

__global__ void prep3(const float* __restrict__ D, const float* __restrict__ GD,
                      const float* __restrict__ alphap, float* __restrict__ St) {
    int gid = blockIdx.x * 256 + threadIdx.x;   // 65536 threads
    int j = gid >> 8, i = gid & 255;
    float inva = 1.0f / alphap[0];
    float s = 0.f;
    #pragma unroll 8
    for (int k = 0; k < 256; ++k) s += D[k*256+i] * GD[k*256+j];
    St[gid] = ((i == j) ? 1.0f : 0.0f) - inva * s;
}

// ---------------- scan kernel: one block per batch row ----------------
__launch_bounds__(256)
__global__ void scan_kernel(const float* __restrict__ y,
                            const float* __restrict__ Pt, const float* __restrict__ St,
                            const float* __restrict__ Wt, const float* __restrict__ Dt,
                            const float* __restrict__ h0, const float* __restrict__ U,
                            const float* __restrict__ lam1p, const float* __restrict__ lam2p,
                            const float* __restrict__ alphap,
                            float* __restrict__ out) {
    __shared__ float Sl[SL_ROWS * DIMN];   // 128 KB: S^T rows 0..127
    __shared__ float hbuf[2][DIMN];        // double-buffered h vector
    __shared__ float ycol[DIMN];           // y[b][:, t]
    __shared__ float htile[DIMN * 16];     // htile[d*16+tt] = h_{t0+tt}[d]

    const int b = blockIdx.x;
    const int i = threadIdx.x;

    const float inva = 1.0f / alphap[0];
    const float bthr = lam1p[0] * inva;
    const float c2   = lam2p[0] * inva;
    const float ui   = U[i] * bthr;

    // stage lower half of S^T into LDS (coalesced)
    for (int r = i; r < SL_ROWS * DIMN; r += 256) Sl[r] = St[r];
    hbuf[0][i] = h0[i];
    __syncthreads();

    const float* yb   = y   + (size_t)b * DIMN * TLEN;
    float*       outb = out + (size_t)b * DIMN * TLEN;

    int cur = 0;   // hbuf[cur] holds h_pre
    for (int t = 0; t < TLEN; ++t) {
        // stage y[b][:,t] (scatter read; lines reused over 16 steps via L2)
        ycol[i] = yb[(size_t)i * TLEN + t];

        // Ph_i = sum_j P[i][j] h_pre[j]   (reads hbuf[cur], valid from last sync)
        float ph = 0.f;
        #pragma unroll 8
        for (int j = 0; j < DIMN; ++j) ph += Pt[j*DIMN+i] * hbuf[cur][j];
        __syncthreads();   // ycol visible; all readers of hbuf done

        // wz_i = sum_d W[i][d] y[b][d][t]  (1/alpha folded into Wt)
        float wz = 0.f;
        #pragma unroll 8
        for (int d = 0; d < DIMN; ++d) wz += Wt[d*DIMN+i] * ycol[d];
        const float cst = wz + c2 * ph;

        int bufc = cur ^ 1;
        hbuf[bufc][i] = ph;     // h starts as Ph
        __syncthreads();

        float h = ph;
        #pragma unroll
        for (int it = 0; it < 4; ++it) {
            float z = 0.f;
            #pragma unroll 8
            for (int j = 0; j < SL_ROWS; ++j)
                z += Sl[j*DIMN+i] * hbuf[bufc][j];
            #pragma unroll 8
            for (int j = SL_ROWS; j < DIMN; ++j)
                z += St[j*DIMN+i] * hbuf[bufc][j];
            z += cst;
            float a = fabsf(z) - ui;
            h = (a > 0.f) ? copysignf(a, z) : 0.f;
            bufc ^= 1;
            hbuf[bufc][i] = h;
            __syncthreads();
        }
        cur = bufc;                     // h_t becomes h_pre of next step
        htile[i*16 + (t & 15)] = h;     // stash for the output projection

        if ((t & 15) == 15) {
            __syncthreads();            // all htile columns complete
            // out[b][n][t0+tt] = sum_d D[n][d] * htile[d][tt]   (n = i)
            const int t0 = t - 15;
            float acc[16];
            #pragma unroll
            for (int tt = 0; tt < 16; ++tt) acc[tt] = 0.f;
            #pragma unroll 4
            for (int d = 0; d < DIMN; ++d) {
                float dv = Dt[d*DIMN + i];
                const float4* hp = (const float4*)&htile[d*16];
                float4 a0 = hp[0], a1 = hp[1], a2 = hp[2], a3 = hp[3];
                acc[0]  += dv * a0.x; acc[1]  += dv * a0.y; acc[2]  += dv * a0.z; acc[3]  += dv * a0.w;
                acc[4]  += dv * a1.x; acc[5]  += dv * a1.y; acc[6]  += dv * a1.z; acc[7]  += dv * a1.w;
                acc[8]  += dv * a2.x; acc[9]  += dv * a2.y; acc[10] += dv * a2.z; acc[11] += dv * a2.w;
                acc[12] += dv * a3.x; acc[13] += dv * a3.y; acc[14] += dv * a3.z; acc[15] += dv * a3.w;
            }
            float* op = outb + (size_t)i * TLEN + t0;
            ((float4*)op)[0] = make_float4(acc[0],  acc[1],  acc[2],  acc[3]);
            ((float4*)op)[1] = make_float4(acc[4],  acc[5],  acc[6],  acc[7]);
            ((float4*)op)[2] = make_float4(acc[8],  acc[9],  acc[10], acc[11]);
            ((float4*)op)[3] = make_float4(acc[12], acc[13], acc[14], acc[15]);
            __syncthreads();            // htile free to be overwritten
        }
    }
}

extern "C" void kernel_launch(void* const* d_in, const int* in_sizes, int n_in,
                              void* d_out, int out_size, void* d_ws, size_t ws_size,
                              hipStream_t stream) {
    const float* y     = (const float*)d_in[0];   // (256,256,256)
    const float* A     = (const float*)d_in[1];   // (64,256)
    const float* D     = (const float*)d_in[2];   // (256,256)
    const float* F     = (const float*)d_in[3];   // (256,256)
    const float* lam1  = (const float*)d_in[4];
    const float* lam2  = (const float*)d_in[5];
    const float* alpha = (const float*)d_in[6];
    const float* h0    = (const float*)d_in[7];   // (256,)
    const float* U     = (const float*)d_in[8];   // (256,)
    float* out = (float*)d_out;

    float* ws = (float*)d_ws;
    float* Pt = ws;                // 65536
    float* St = ws + 65536;        // 65536
    float* Wt = ws + 131072;       // 65536
    float* Dt = ws + 196608;       // 65536
    float* FD = ws + 262144;       // 65536
    float* G  = ws + 327680;       // 65536
    float* GD = ws + 393216;       // 65536
    float* AD = ws + 458752;       // 16384
    // total 475136 floats ~ 1.9 MB of ws

    prep1<<<832, 256, 0, stream>>>(A, D, F, lam2, FD, G, AD, Dt);
    prep2<<<768, 256, 0, stream>>>(A, D, alpha, FD, G, AD, Pt, GD, Wt);
    prep3<<<256, 256, 0, stream>>>(D, GD, alpha, St);
    scan_kernel<<<256, 256, 0, stream>>>(y, Pt, St, Wt, Dt, h0, U,
                                         lam1, lam2, alpha, out);
}

// Round 2
// 1364.590 us; speedup vs baseline: 4.8484x; 4.8484x over previous
//
#include <hip/hip_runtime.h>
#include <hip/hip_bf16.h>

typedef unsigned int u32;
typedef unsigned short u16;

#define DIMN 256
#define TLEN 256

// ---------------------------------------------------------------------------
// dot2 helper: fp16 pair dot with fp32 accumulate (v_dot2_f32_f16)
// ---------------------------------------------------------------------------
typedef _Float16 half2v __attribute__((ext_vector_type(2)));

__device__ __forceinline__ float dot2f(u32 a, u32 b, float c) {
#if __has_builtin(__builtin_amdgcn_fdot2)
    half2v ah = __builtin_bit_cast(half2v, a);
    half2v bh = __builtin_bit_cast(half2v, b);
    return __builtin_amdgcn_fdot2(ah, bh, c, false);
#else
    half2v ah = __builtin_bit_cast(half2v, a);
    half2v bh = __builtin_bit_cast(half2v, b);
    return c + (float)ah.x * (float)bh.x + (float)ah.y * (float)bh.y;
#endif
}

__device__ __forceinline__ u32 packh2(float lo, float hi) {
    _Float16 l = (_Float16)lo, h = (_Float16)hi;
    u16 lu = __builtin_bit_cast(u16, l);
    u16 hu = __builtin_bit_cast(u16, h);
    return (u32)lu | ((u32)hu << 16);
}

union F4U { float4 f; u32 u[4]; };

// ---------------------------------------------------------------------------
// prep kernels (shared by both paths): build P^T, S^T, W^T, D^T
//   Pt[j*256+i] = P[i][j],  P = D^T F D
//   St[j*256+i] = S[i][j],  S = I - (1/a) D^T (A^T A + lam2 I) D
//   Wt[d*256+i] = W[i][d],  W = (1/a) D^T A^T A
//   Dt[d*256+n] = D[n][d]
// ---------------------------------------------------------------------------
__global__ void prep1(const float* __restrict__ A, const float* __restrict__ D,
                      const float* __restrict__ F, const float* __restrict__ lam2p,
                      float* __restrict__ FD, float* __restrict__ G,
                      float* __restrict__ AD, float* __restrict__ Dt) {
    int gid = blockIdx.x * 256 + threadIdx.x;
    if (gid < 65536) {                   // FD[k][j] = sum_q F[k][q] D[q][j]
        int k = gid >> 8, j = gid & 255;
        float s = 0.f;
        #pragma unroll 8
        for (int q = 0; q < 256; ++q) s += F[k*256+q] * D[q*256+j];
        FD[gid] = s;
    } else if (gid < 131072) {           // G[p][q] = sum_m A[m][p] A[m][q] + lam2*(p==q)
        int g = gid - 65536; int p = g >> 8, q = g & 255;
        float s = (p == q) ? lam2p[0] : 0.f;
        #pragma unroll 8
        for (int m = 0; m < 64; ++m) s += A[m*256+p] * A[m*256+q];
        G[g] = s;
    } else if (gid < 147456) {           // AD[m][i] = sum_k A[m][k] D[k][i]
        int g = gid - 131072; int m = g >> 8, i = g & 255;
        float s = 0.f;
        #pragma unroll 8
        for (int k = 0; k < 256; ++k) s += A[m*256+k] * D[k*256+i];
        AD[g] = s;
    } else if (gid < 212992) {           // Dt[d][n] = D[n][d]
        int g = gid - 147456; int d = g >> 8, n = g & 255;
        Dt[g] = D[n*256+d];
    }
}

__global__ void prep2(const float* __restrict__ A, const float* __restrict__ D,
                      const float* __restrict__ alphap,
                      const float* __restrict__ FD, const float* __restrict__ G,
                      const float* __restrict__ AD,
                      float* __restrict__ Pt, float* __restrict__ GD,
                      float* __restrict__ Wt) {
    int gid = blockIdx.x * 256 + threadIdx.x;
    float inva = 1.0f / alphap[0];
    if (gid < 65536) {                   // Pt[j][i] = sum_k D[k][i] FD[k][j]
        int j = gid >> 8, i = gid & 255;
        float s = 0.f;
        #pragma unroll 8
        for (int k = 0; k < 256; ++k) s += D[k*256+i] * FD[k*256+j];
        Pt[gid] = s;
    } else if (gid < 131072) {           // GD[k][j] = sum_q G[k][q] D[q][j]
        int g = gid - 65536; int k = g >> 8, j = g & 255;
        float s = 0.f;
        #pragma unroll 8
        for (int q = 0; q < 256; ++q) s += G[k*256+q] * D[q*256+j];
        GD[g] = s;
    } else {                             // Wt[d][i] = inva * sum_m AD[m][i] A[m][d]
        int g = gid - 131072; int d = g >> 8, i = g & 255;
        float s = 0.f;
        #pragma unroll 8
        for (int m = 0; m < 64; ++m) s += AD[m*256+i] * A[m*256+d];
        Wt[g] = inva * s;
    }
}

__global__ void prep3(const float* __restrict__ D, const float* __restrict__ GD,
                      const float* __restrict__ alphap, float* __restrict__ St) {
    int gid = blockIdx.x * 256 + threadIdx.x;   // 65536 threads
    int j = gid >> 8, i = gid & 255;
    float inva = 1.0f / alphap[0];
    float s = 0.f;
    #pragma unroll 8
    for (int k = 0; k < 256; ++k) s += D[k*256+i] * GD[k*256+j];
    St[gid] = ((i == j) ? 1.0f : 0.0f) - inva * s;
}

// pack S^T / P^T into half2-pair layout: Xh[jp*256+i] = (X[i][2jp], X[i][2jp+1])
__global__ void prep4(const float* __restrict__ St, const float* __restrict__ Pt,
                      u32* __restrict__ Sth, u32* __restrict__ Pth) {
    int gid = blockIdx.x * 256 + threadIdx.x;   // 65536 threads
    int g = gid & 32767;
    int jp = g >> 8, i = g & 255;
    if (gid < 32768)
        Sth[g] = packh2(St[(2*jp)*256 + i], St[(2*jp+1)*256 + i]);
    else
        Pth[g] = packh2(Pt[(2*jp)*256 + i], Pt[(2*jp+1)*256 + i]);
}

// ---------------------------------------------------------------------------
// Z-GEMM: Z[b][t][i] = sum_d Wt[d*256+i] * y[b][d][t]   (fp32)
// tile: 64t x 64i per block, 4x4 micro-tile per thread
// ---------------------------------------------------------------------------
__launch_bounds__(256)
__global__ void zgemm(const float* __restrict__ y, const float* __restrict__ Wt,
                      float* __restrict__ Z) {
    __shared__ float ys[64][65];    // [dd][tt]
    __shared__ float wsh[64][65];   // [dd][ii]
    const int b  = blockIdx.x;
    const int t0 = (blockIdx.y & 3) * 64;
    const int i0 = (blockIdx.y >> 2) * 64;
    const int tid = threadIdx.x;
    const int tx = tid & 15;   // i-quad
    const int ty = tid >> 4;   // t-quad
    float acc[4][4];
    #pragma unroll
    for (int c = 0; c < 4; ++c)
        #pragma unroll
        for (int a = 0; a < 4; ++a) acc[c][a] = 0.f;

    for (int dc = 0; dc < 256; dc += 64) {
        #pragma unroll
        for (int r = 0; r < 16; ++r) {
            int idx = r * 256 + tid;
            int row = idx >> 6, col = idx & 63;
            ys[row][col]  = y[((size_t)b*256 + dc + row)*256 + t0 + col];
            wsh[row][col] = Wt[(size_t)(dc + row)*256 + i0 + col];
        }
        __syncthreads();
        #pragma unroll 8
        for (int dd = 0; dd < 64; ++dd) {
            float wv[4], yv[4];
            #pragma unroll
            for (int a = 0; a < 4; ++a) wv[a] = wsh[dd][4*tx + a];
            #pragma unroll
            for (int c = 0; c < 4; ++c) yv[c] = ys[dd][4*ty + c];
            #pragma unroll
            for (int c = 0; c < 4; ++c)
                #pragma unroll
                for (int a = 0; a < 4; ++a) acc[c][a] += wv[a] * yv[c];
        }
        __syncthreads();
    }
    #pragma unroll
    for (int c = 0; c < 4; ++c) {
        float4 v = make_float4(acc[c][0], acc[c][1], acc[c][2], acc[c][3]);
        *(float4*)&Z[((size_t)b*256 + t0 + 4*ty + c)*256 + i0 + 4*tx] = v;
    }
}

// ---------------------------------------------------------------------------
// scan2: 256 blocks (one per batch row) x 512 threads.
//   waves 0-3 (tid<256): hold S row i in VGPRs, run the 4 ISTA iterations
//   waves 4-7 (tid>=256): hold P row i in VGPRs, compute Ph + const
// h lives in LDS as fp16, double-buffered. 5 barriers per step.
// ---------------------------------------------------------------------------
__launch_bounds__(512, 2)
__global__ void scan2(const u32* __restrict__ Sth, const u32* __restrict__ Pth,
                      const float* __restrict__ Z,
                      const float* __restrict__ h0, const float* __restrict__ U,
                      const float* __restrict__ lam1p, const float* __restrict__ lam2p,
                      const float* __restrict__ alphap,
                      float* __restrict__ H) {
    __shared__ __align__(16) _Float16 hb[2][DIMN];
    __shared__ float cst[DIMN];

    const int b    = blockIdx.x;
    const int tid  = threadIdx.x;
    const int role = tid >> 8;       // 0 = S-group, 1 = P-group
    const int i    = tid & 255;

    const float inva = 1.0f / alphap[0];
    const float bt   = lam1p[0] * inva;
    const float c2   = lam2p[0] * inva;
    const float ui   = U[i] * bt;

    // load this thread's matrix row (128 packed half2) into registers
    const u32* msrc = role ? Pth : Sth;
    u32 mreg[128];
    #pragma unroll
    for (int jp = 0; jp < 128; ++jp) mreg[jp] = msrc[jp*256 + i];

    if (role == 0) hb[0][i] = (_Float16)h0[i];
    __syncthreads();

    const float* Zb = Z + (size_t)b * TLEN * DIMN;
    float*       Hb = H + (size_t)b * TLEN * DIMN;

    float zc = 0.f;
    if (role == 1) zc = Zb[i];          // prefetch Z col for t=0

    int cur = 0;
    #pragma unroll 1
    for (int t = 0; t < TLEN; ++t) {
        // ---- P-phase: ph = P[i] . h_{t-1};  const = Z + c2*ph ----
        if (role == 1) {
            float a0 = 0.f, a1 = 0.f, a2 = 0.f, a3 = 0.f;
            const float4* hp = (const float4*)(&hb[cur][0]);
            #pragma unroll
            for (int k = 0; k < 32; ++k) {
                F4U u; u.f = hp[k];
                a0 = dot2f(mreg[4*k+0], u.u[0], a0);
                a1 = dot2f(mreg[4*k+1], u.u[1], a1);
                a2 = dot2f(mreg[4*k+2], u.u[2], a2);
                a3 = dot2f(mreg[4*k+3], u.u[3], a3);
            }
            float ph = (a0 + a1) + (a2 + a3);
            cst[i] = zc + c2 * ph;
            hb[cur ^ 1][i] = (_Float16)ph;
            // prefetch next step's Z column (covered by the 4 S-iters)
            int tn = (t < TLEN-1) ? (t+1) : t;
            zc = Zb[(size_t)tn * DIMN + i];
        }
        __syncthreads();                 // barrier 1: const + Ph visible

        float creg = 0.f, hlast = 0.f;
        if (role == 0) creg = cst[i];

        int buf = cur ^ 1;
        #pragma unroll
        for (int it = 0; it < 4; ++it) {
            if (role == 0) {
                float a0 = 0.f, a1 = 0.f, a2 = 0.f, a3 = 0.f;
                const float4* hp = (const float4*)(&hb[buf][0]);
                #pragma unroll
                for (int k = 0; k < 32; ++k) {
                    F4U u; u.f = hp[k];
                    a0 = dot2f(mreg[4*k+0], u.u[0], a0);
                    a1 = dot2f(mreg[4*k+1], u.u[1], a1);
                    a2 = dot2f(mreg[4*k+2], u.u[2], a2);
                    a3 = dot2f(mreg[4*k+3], u.u[3], a3);
                }
                float z = ((a0 + a1) + (a2 + a3)) + creg;
                float aa = fabsf(z) - ui;
                float h = (aa > 0.f) ? copysignf(aa, z) : 0.f;
                hb[buf ^ 1][i] = (_Float16)h;
                hlast = h;
            }
            __syncthreads();             // barriers 2-5
            buf ^= 1;
        }
        if (role == 0) Hb[(size_t)t * DIMN + i] = hlast;
        cur ^= 1;                        // final h landed in hb[cur^1]
    }
}

// ---------------------------------------------------------------------------
// out-GEMM: out[b][n][t] = sum_d D[n][d] * H[b][t][d]
// tile: 64n x 64t per block, 4x4 micro-tile
// ---------------------------------------------------------------------------
__launch_bounds__(256)
__global__ void ogemm(const float* __restrict__ D, const float* __restrict__ H,
                      float* __restrict__ out) {
    __shared__ float Ds[64][65];   // [dd][nn]
    __shared__ float Hs[64][65];   // [dd][tt]
    const int b  = blockIdx.x;
    const int n0 = (blockIdx.y & 3) * 64;
    const int t0 = (blockIdx.y >> 2) * 64;
    const int tid = threadIdx.x;
    const int tx = tid & 15;   // n-quad
    const int ty = tid >> 4;   // t-quad
    float acc[4][4];
    #pragma unroll
    for (int c = 0; c < 4; ++c)
        #pragma unroll
        for (int a = 0; a < 4; ++a) acc[c][a] = 0.f;

    for (int dc = 0; dc < 256; dc += 64) {
        #pragma unroll
        for (int r = 0; r < 16; ++r) {
            int idx = r * 256 + tid;
            int row = idx >> 6, col = idx & 63;    // row = nn or tt, col = dd
            Ds[col][row] = D[(size_t)(n0 + row)*256 + dc + col];
            Hs[col][row] = H[((size_t)b*256 + t0 + row)*256 + dc + col];
        }
        __syncthreads();
        #pragma unroll 8
        for (int dd = 0; dd < 64; ++dd) {
            float dv[4], hv[4];
            #pragma unroll
            for (int a = 0; a < 4; ++a) dv[a] = Ds[dd][4*tx + a];
            #pragma unroll
            for (int c = 0; c < 4; ++c) hv[c] = Hs[dd][4*ty + c];
            #pragma unroll
            for (int c = 0; c < 4; ++c)
                #pragma unroll
                for (int a = 0; a < 4; ++a) acc[c][a] += dv[a] * hv[c];
        }
        __syncthreads();
    }
    #pragma unroll
    for (int a = 0; a < 4; ++a) {
        float4 v = make_float4(acc[0][a], acc[1][a], acc[2][a], acc[3][a]);
        *(float4*)&out[((size_t)b*256 + n0 + 4*tx + a)*256 + t0 + 4*ty] = v;
    }
}

// ---------------------------------------------------------------------------
// fallback path B (round-1 kernel): used when ws is too small for Z/H
// ---------------------------------------------------------------------------
#define SL_ROWS 128
__launch_bounds__(256)
__global__ void scan_kernel(const float* __restrict__ y,
                            const float* __restrict__ Pt, const float* __restrict__ St,
                            const float* __restrict__ Wt, const float* __restrict__ Dt,
                            const float* __restrict__ h0, const float* __restrict__ U,
                            const float* __restrict__ lam1p, const float* __restrict__ lam2p,
                            const float* __restrict__ alphap,
                            float* __restrict__ out) {
    __shared__ float Sl[SL_ROWS * DIMN];
    __shared__ float hbuf[2][DIMN];
    __shared__ float ycol[DIMN];
    __shared__ float htile[DIMN * 16];

    const int b = blockIdx.x;
    const int i = threadIdx.x;

    const float inva = 1.0f / alphap[0];
    const float bthr = lam1p[0] * inva;
    const float c2   = lam2p[0] * inva;
    const float ui   = U[i] * bthr;

    for (int r = i; r < SL_ROWS * DIMN; r += 256) Sl[r] = St[r];
    hbuf[0][i] = h0[i];
    __syncthreads();

    const float* yb   = y   + (size_t)b * DIMN * TLEN;
    float*       outb = out + (size_t)b * DIMN * TLEN;

    int cur = 0;
    for (int t = 0; t < TLEN; ++t) {
        ycol[i] = yb[(size_t)i * TLEN + t];
        float ph = 0.f;
        #pragma unroll 8
        for (int j = 0; j < DIMN; ++j) ph += Pt[j*DIMN+i] * hbuf[cur][j];
        __syncthreads();
        float wz = 0.f;
        #pragma unroll 8
        for (int d = 0; d < DIMN; ++d) wz += Wt[d*DIMN+i] * ycol[d];
        const float cst = wz + c2 * ph;
        int bufc = cur ^ 1;
        hbuf[bufc][i] = ph;
        __syncthreads();
        float h = ph;
        #pragma unroll
        for (int it = 0; it < 4; ++it) {
            float z = 0.f;
            #pragma unroll 8
            for (int j = 0; j < SL_ROWS; ++j) z += Sl[j*DIMN+i] * hbuf[bufc][j];
            #pragma unroll 8
            for (int j = SL_ROWS; j < DIMN; ++j) z += St[j*DIMN+i] * hbuf[bufc][j];
            z += cst;
            float a = fabsf(z) - ui;
            h = (a > 0.f) ? copysignf(a, z) : 0.f;
            bufc ^= 1;
            hbuf[bufc][i] = h;
            __syncthreads();
        }
        cur = bufc;
        htile[i*16 + (t & 15)] = h;
        if ((t & 15) == 15) {
            __syncthreads();
            const int t0 = t - 15;
            float acc[16];
            #pragma unroll
            for (int tt = 0; tt < 16; ++tt) acc[tt] = 0.f;
            #pragma unroll 4
            for (int d = 0; d < DIMN; ++d) {
                float dv = Dt[d*DIMN + i];
                const float4* hp = (const float4*)&htile[d*16];
                float4 a0 = hp[0], a1 = hp[1], a2 = hp[2], a3 = hp[3];
                acc[0]  += dv * a0.x; acc[1]  += dv * a0.y; acc[2]  += dv * a0.z; acc[3]  += dv * a0.w;
                acc[4]  += dv * a1.x; acc[5]  += dv * a1.y; acc[6]  += dv * a1.z; acc[7]  += dv * a1.w;
                acc[8]  += dv * a2.x; acc[9]  += dv * a2.y; acc[10] += dv * a2.z; acc[11] += dv * a2.w;
                acc[12] += dv * a3.x; acc[13] += dv * a3.y; acc[14] += dv * a3.z; acc[15] += dv * a3.w;
            }
            float* op = outb + (size_t)i * TLEN + t0;
            ((float4*)op)[0] = make_float4(acc[0],  acc[1],  acc[2],  acc[3]);
            ((float4*)op)[1] = make_float4(acc[4],  acc[5],  acc[6],  acc[7]);
            ((float4*)op)[2] = make_float4(acc[8],  acc[9],  acc[10], acc[11]);
            ((float4*)op)[3] = make_float4(acc[12], acc[13], acc[14], acc[15]);
            __syncthreads();
        }
    }
}

// ---------------------------------------------------------------------------
extern "C" void kernel_launch(void* const* d_in, const int* in_sizes, int n_in,
                              void* d_out, int out_size, void* d_ws, size_t ws_size,
                              hipStream_t stream) {
    const float* y     = (const float*)d_in[0];
    const float* A     = (const float*)d_in[1];
    const float* D     = (const float*)d_in[2];
    const float* F     = (const float*)d_in[3];
    const float* lam1  = (const float*)d_in[4];
    const float* lam2  = (const float*)d_in[5];
    const float* alpha = (const float*)d_in[6];
    const float* h0    = (const float*)d_in[7];
    const float* U     = (const float*)d_in[8];
    float* out = (float*)d_out;
    float* ws  = (float*)d_ws;

    // path-A ws layout (element offsets, fp32 unless noted)
    const size_t oZ  = 0;
    const size_t oH  = 16777216;
    const size_t oWt = 33554432;
    const size_t oSt = 33619968;
    const size_t oPt = 33685504;
    const size_t oFD = 33751040;
    const size_t oG  = 33816576;
    const size_t oGD = 33882112;
    const size_t oAD = 33947648;
    const size_t oDt = 33964032;
    const size_t oSh = 34029568;   // u32
    const size_t oPh = 34062336;   // u32
    const size_t NEED = (size_t)34095104 * 4;

    if (ws_size >= NEED) {
        float* Z  = ws + oZ;  float* H  = ws + oH;
        float* Wt = ws + oWt; float* St = ws + oSt; float* Pt = ws + oPt;
        float* FD = ws + oFD; float* G  = ws + oG;  float* GD = ws + oGD;
        float* AD = ws + oAD; float* Dt = ws + oDt;
        u32* Sth = (u32*)(ws + oSh);
        u32* Pth = (u32*)(ws + oPh);

        prep1<<<832, 256, 0, stream>>>(A, D, F, lam2, FD, G, AD, Dt);
        prep2<<<768, 256, 0, stream>>>(A, D, alpha, FD, G, AD, Pt, GD, Wt);
        prep3<<<256, 256, 0, stream>>>(D, GD, alpha, St);
        prep4<<<256, 256, 0, stream>>>(St, Pt, Sth, Pth);
        {
            dim3 g(256, 16);
            zgemm<<<g, 256, 0, stream>>>(y, Wt, Z);
        }
        scan2<<<256, 512, 0, stream>>>(Sth, Pth, Z, h0, U, lam1, lam2, alpha, H);
        {
            dim3 g(256, 16);
            ogemm<<<g, 256, 0, stream>>>(D, H, out);
        }
    } else {
        // fallback: round-1 compact layout
        float* Pt = ws;
        float* St = ws + 65536;
        float* Wt = ws + 131072;
        float* Dt = ws + 196608;
        float* FD = ws + 262144;
        float* G  = ws + 327680;
        float* GD = ws + 393216;
        float* AD = ws + 458752;
        prep1<<<832, 256, 0, stream>>>(A, D, F, lam2, FD, G, AD, Dt);
        prep2<<<768, 256, 0, stream>>>(A, D, alpha, FD, G, AD, Pt, GD, Wt);
        prep3<<<256, 256, 0, stream>>>(D, GD, alpha, St);
        scan_kernel<<<256, 256, 0, stream>>>(y, Pt, St, Wt, Dt, h0, U,
                                             lam1, lam2, alpha, out);
    }
}

// Round 3
// 1048.312 us; speedup vs baseline: 6.3112x; 1.3017x over previous
//
#include <hip/hip_runtime.h>
#include <hip/hip_bf16.h>

typedef unsigned int u32;
typedef unsigned short u16;

#define DIMN 256
#define TLEN 256

// ---------------------------------------------------------------------------
// dot2 helper: fp16 pair dot with fp32 accumulate (v_dot2_f32_f16)
// ---------------------------------------------------------------------------
typedef _Float16 half2v __attribute__((ext_vector_type(2)));

__device__ __forceinline__ float dot2f(u32 a, u32 b, float c) {
#if __has_builtin(__builtin_amdgcn_fdot2)
    half2v ah = __builtin_bit_cast(half2v, a);
    half2v bh = __builtin_bit_cast(half2v, b);
    return __builtin_amdgcn_fdot2(ah, bh, c, false);
#else
    half2v ah = __builtin_bit_cast(half2v, a);
    half2v bh = __builtin_bit_cast(half2v, b);
    return c + (float)ah.x * (float)bh.x + (float)ah.y * (float)bh.y;
#endif
}

__device__ __forceinline__ u32 packh2(float lo, float hi) {
    _Float16 l = (_Float16)lo, h = (_Float16)hi;
    u16 lu = __builtin_bit_cast(u16, l);
    u16 hu = __builtin_bit_cast(u16, h);
    return (u32)lu | ((u32)hu << 16);
}

union F4U { float4 f; u32 u[4]; };

// ---------------------------------------------------------------------------
// prep kernels: build P^T, S^T, W^T (fp32) then pack S^T/P^T to half2 pairs
//   Pt[j*256+i] = P[i][j],  P = D^T F D
//   St[j*256+i] = S[i][j],  S = I - (1/a) D^T (A^T A + lam2 I) D
//   Wt[d*256+i] = W[i][d],  W = (1/a) D^T A^T A
// ---------------------------------------------------------------------------
__global__ void prep1(const float* __restrict__ A, const float* __restrict__ D,
                      const float* __restrict__ F, const float* __restrict__ lam2p,
                      float* __restrict__ FD, float* __restrict__ G,
                      float* __restrict__ AD) {
    int gid = blockIdx.x * 256 + threadIdx.x;
    if (gid < 65536) {                   // FD[k][j] = sum_q F[k][q] D[q][j]
        int k = gid >> 8, j = gid & 255;
        float s = 0.f;
        #pragma unroll 8
        for (int q = 0; q < 256; ++q) s += F[k*256+q] * D[q*256+j];
        FD[gid] = s;
    } else if (gid < 131072) {           // G[p][q] = sum_m A[m][p] A[m][q] + lam2*(p==q)
        int g = gid - 65536; int p = g >> 8, q = g & 255;
        float s = (p == q) ? lam2p[0] : 0.f;
        #pragma unroll 8
        for (int m = 0; m < 64; ++m) s += A[m*256+p] * A[m*256+q];
        G[g] = s;
    } else if (gid < 147456) {           // AD[m][i] = sum_k A[m][k] D[k][i]
        int g = gid - 131072; int m = g >> 8, i = g & 255;
        float s = 0.f;
        #pragma unroll 8
        for (int k = 0; k < 256; ++k) s += A[m*256+k] * D[k*256+i];
        AD[g] = s;
    }
}

__global__ void prep2(const float* __restrict__ A, const float* __restrict__ D,
                      const float* __restrict__ alphap,
                      const float* __restrict__ FD, const float* __restrict__ G,
                      const float* __restrict__ AD,
                      float* __restrict__ Pt, float* __restrict__ GD,
                      float* __restrict__ Wt) {
    int gid = blockIdx.x * 256 + threadIdx.x;
    float inva = 1.0f / alphap[0];
    if (gid < 65536) {                   // Pt[j][i] = sum_k D[k][i] FD[k][j]
        int j = gid >> 8, i = gid & 255;
        float s = 0.f;
        #pragma unroll 8
        for (int k = 0; k < 256; ++k) s += D[k*256+i] * FD[k*256+j];
        Pt[gid] = s;
    } else if (gid < 131072) {           // GD[k][j] = sum_q G[k][q] D[q][j]
        int g = gid - 65536; int k = g >> 8, j = g & 255;
        float s = 0.f;
        #pragma unroll 8
        for (int q = 0; q < 256; ++q) s += G[k*256+q] * D[q*256+j];
        GD[g] = s;
    } else {                             // Wt[d][i] = inva * sum_m AD[m][i] A[m][d]
        int g = gid - 131072; int d = g >> 8, i = g & 255;
        float s = 0.f;
        #pragma unroll 8
        for (int m = 0; m < 64; ++m) s += AD[m*256+i] * A[m*256+d];
        Wt[g] = inva * s;
    }
}

__global__ void prep3(const float* __restrict__ D, const float* __restrict__ GD,
                      const float* __restrict__ alphap, float* __restrict__ St) {
    int gid = blockIdx.x * 256 + threadIdx.x;   // 65536 threads
    int j = gid >> 8, i = gid & 255;
    float inva = 1.0f / alphap[0];
    float s = 0.f;
    #pragma unroll 8
    for (int k = 0; k < 256; ++k) s += D[k*256+i] * GD[k*256+j];
    St[gid] = ((i == j) ? 1.0f : 0.0f) - inva * s;
}

// pack: Xh[jp*256+i] = (X[i][2jp], X[i][2jp+1])
__global__ void prep4(const float* __restrict__ St, const float* __restrict__ Pt,
                      u32* __restrict__ Sth, u32* __restrict__ Pth) {
    int gid = blockIdx.x * 256 + threadIdx.x;   // 65536 threads
    int g = gid & 32767;
    int jp = g >> 8, i = g & 255;
    if (gid < 32768)
        Sth[g] = packh2(St[(2*jp)*256 + i], St[(2*jp+1)*256 + i]);
    else
        Pth[g] = packh2(Pt[(2*jp)*256 + i], Pt[(2*jp+1)*256 + i]);
}

// ---------------------------------------------------------------------------
// Z-GEMM: Z[b][t][i] = sum_d Wt[d*256+i] * y[b][d][t]   (fp32)
// 128x128 tile per block, 8x8 micro-tile, float4 LDS reads
// ---------------------------------------------------------------------------
__launch_bounds__(256, 2)
__global__ void zgemm(const float* __restrict__ y, const float* __restrict__ Wt,
                      float* __restrict__ Z) {
    __shared__ float ys[64][132];    // [dd][tt]
    __shared__ float wsh[64][132];   // [dd][ii]
    const int b  = blockIdx.x;
    const int t0 = (blockIdx.y & 1) * 128;
    const int i0 = (blockIdx.y >> 1) * 128;
    const int tid = threadIdx.x;
    const int tx = tid & 15;   // i-octet
    const int ty = tid >> 4;   // t-octet
    float acc[8][8];           // [c=t][a=i]
    #pragma unroll
    for (int c = 0; c < 8; ++c)
        #pragma unroll
        for (int a = 0; a < 8; ++a) acc[c][a] = 0.f;

    for (int dc = 0; dc < 256; dc += 64) {
        #pragma unroll
        for (int k = 0; k < 8; ++k) {
            int idx = k * 256 + tid;           // 2048 float4 per array
            int row = idx >> 5, col4 = idx & 31;
            float4 yv = *(const float4*)&y[((size_t)b*256 + dc + row)*256 + t0 + col4*4];
            float4 wv = *(const float4*)&Wt[(size_t)(dc + row)*256 + i0 + col4*4];
            *(float4*)&ys[row][col4*4]  = yv;
            *(float4*)&wsh[row][col4*4] = wv;
        }
        __syncthreads();
        #pragma unroll 4
        for (int dd = 0; dd < 64; ++dd) {
            float4 w0 = *(const float4*)&wsh[dd][8*tx];
            float4 w1 = *(const float4*)&wsh[dd][8*tx+4];
            float4 y0 = *(const float4*)&ys[dd][8*ty];
            float4 y1 = *(const float4*)&ys[dd][8*ty+4];
            float wv[8] = {w0.x,w0.y,w0.z,w0.w,w1.x,w1.y,w1.z,w1.w};
            float yv[8] = {y0.x,y0.y,y0.z,y0.w,y1.x,y1.y,y1.z,y1.w};
            #pragma unroll
            for (int c = 0; c < 8; ++c)
                #pragma unroll
                for (int a = 0; a < 8; ++a) acc[c][a] += wv[a] * yv[c];
        }
        __syncthreads();
    }
    #pragma unroll
    for (int c = 0; c < 8; ++c) {
        float* zp = &Z[((size_t)b*256 + t0 + 8*ty + c)*256 + i0 + 8*tx];
        *(float4*)(zp)     = make_float4(acc[c][0], acc[c][1], acc[c][2], acc[c][3]);
        *(float4*)(zp + 4) = make_float4(acc[c][4], acc[c][5], acc[c][6], acc[c][7]);
    }
}

// ---------------------------------------------------------------------------
// scan3: 256 blocks (one per batch row) x 1024 threads.
// Thread (i = tid&255, q = tid>>8) holds the q-th K-quarter of S-row-i and
// P-row-i in VGPRs (32+32 packed half2). Every wave works in every phase;
// 4-way partial reduce through LDS.
// ---------------------------------------------------------------------------
__launch_bounds__(1024, 4)
__global__ void scan3(const u32* __restrict__ Sth, const u32* __restrict__ Pth,
                      const float* __restrict__ Z,
                      const float* __restrict__ h0, const float* __restrict__ U,
                      const float* __restrict__ lam1p, const float* __restrict__ lam2p,
                      const float* __restrict__ alphap,
                      float* __restrict__ H) {
    __shared__ __align__(16) _Float16 hb[2][DIMN];
    __shared__ float part[4][DIMN];

    const int tid = threadIdx.x;
    const int i   = tid & 255;
    const int q   = tid >> 8;
    const int b   = blockIdx.x;

    const float inva = 1.0f / alphap[0];
    const float bt   = lam1p[0] * inva;
    const float c2   = lam2p[0] * inva;
    const float ui   = U[i] * bt;

    // matrix row quarters -> registers (coalesced: i consecutive per wave)
    u32 Sq[32], Pq[32];
    #pragma unroll
    for (int jp = 0; jp < 32; ++jp) {
        Sq[jp] = Sth[(q*32 + jp)*256 + i];
        Pq[jp] = Pth[(q*32 + jp)*256 + i];
    }

    if (tid < 256) hb[0][i] = (_Float16)h0[i];
    __syncthreads();

    const float* Zb = Z + (size_t)b * TLEN * DIMN;
    float*       Hb = H + (size_t)b * TLEN * DIMN;

    float zc = 0.f;
    if (tid < 256) zc = Zb[i];            // Z column for t=0

    int cur = 0;
    #pragma unroll 1
    for (int t = 0; t < TLEN; ++t) {
        // ---- P-phase: partial dot of P-quarter with h_pre quarter ----
        {
            const float4* hp = (const float4*)(&hb[cur][q*64]);   // 8 x b128, broadcast
            float a0 = 0.f, a1 = 0.f, a2 = 0.f, a3 = 0.f;
            #pragma unroll
            for (int k = 0; k < 8; ++k) {
                F4U u; u.f = hp[k];
                a0 = dot2f(Sq[0]*0u + Pq[4*k+0], u.u[0], a0);
                a1 = dot2f(Pq[4*k+1], u.u[1], a1);
                a2 = dot2f(Pq[4*k+2], u.u[2], a2);
                a3 = dot2f(Pq[4*k+3], u.u[3], a3);
            }
            part[q][i] = (a0 + a1) + (a2 + a3);
        }
        __syncthreads();

        float creg = 0.f;
        if (tid < 256) {
            float ph = (part[0][i] + part[1][i]) + (part[2][i] + part[3][i]);
            creg = zc + c2 * ph;
            hb[cur ^ 1][i] = (_Float16)ph;
            int tn = (t < TLEN-1) ? (t+1) : t;
            zc = Zb[(size_t)tn * DIMN + i];   // prefetch next step's Z column
        }
        __syncthreads();

        int buf = cur ^ 1;
        #pragma unroll
        for (int it = 0; it < 4; ++it) {
            {
                const float4* hp = (const float4*)(&hb[buf][q*64]);
                float a0 = 0.f, a1 = 0.f, a2 = 0.f, a3 = 0.f;
                #pragma unroll
                for (int k = 0; k < 8; ++k) {
                    F4U u; u.f = hp[k];
                    a0 = dot2f(Sq[4*k+0], u.u[0], a0);
                    a1 = dot2f(Sq[4*k+1], u.u[1], a1);
                    a2 = dot2f(Sq[4*k+2], u.u[2], a2);
                    a3 = dot2f(Sq[4*k+3], u.u[3], a3);
                }
                part[q][i] = (a0 + a1) + (a2 + a3);
            }
            __syncthreads();
            if (tid < 256) {
                float z = (part[0][i] + part[1][i]) + (part[2][i] + part[3][i]) + creg;
                float aa = fabsf(z) - ui;
                float h = (aa > 0.f) ? copysignf(aa, z) : 0.f;
                hb[buf ^ 1][i] = (_Float16)h;
                if (it == 3) Hb[(size_t)t * DIMN + i] = h;
            }
            __syncthreads();
            buf ^= 1;
        }
        cur = buf;           // hb[cur] now holds h_t
    }
}

// ---------------------------------------------------------------------------
// out-GEMM: out[b][n][t] = sum_d D[n][d] * H[b][t][d]
// 128x128 tile, 8x8 micro-tile; both operands transposed into LDS
// ---------------------------------------------------------------------------
__launch_bounds__(256, 2)
__global__ void ogemm(const float* __restrict__ D, const float* __restrict__ H,
                      float* __restrict__ out) {
    __shared__ float Ds[64][132];   // [dd][nn]
    __shared__ float Hs[64][132];   // [dd][tt]
    const int b  = blockIdx.x;
    const int n0 = (blockIdx.y & 1) * 128;
    const int t0 = (blockIdx.y >> 1) * 128;
    const int tid = threadIdx.x;
    const int tx = tid & 15;   // n-octet
    const int ty = tid >> 4;   // t-octet
    float acc[8][8];           // [a=n][c=t]
    #pragma unroll
    for (int a = 0; a < 8; ++a)
        #pragma unroll
        for (int c = 0; c < 8; ++c) acc[a][c] = 0.f;

    for (int dc = 0; dc < 256; dc += 64) {
        #pragma unroll
        for (int k = 0; k < 8; ++k) {
            int idx = k * 256 + tid;           // 2048 float4 per array
            int row = idx >> 4;                // nn or tt (128 rows)
            int d4  = idx & 15;                // 16 float4 across d-chunk
            float4 dv = *(const float4*)&D[((size_t)(n0 + row))*256 + dc + d4*4];
            float4 hv = *(const float4*)&H[((size_t)b*256 + t0 + row)*256 + dc + d4*4];
            Ds[d4*4+0][row] = dv.x; Ds[d4*4+1][row] = dv.y;
            Ds[d4*4+2][row] = dv.z; Ds[d4*4+3][row] = dv.w;
            Hs[d4*4+0][row] = hv.x; Hs[d4*4+1][row] = hv.y;
            Hs[d4*4+2][row] = hv.z; Hs[d4*4+3][row] = hv.w;
        }
        __syncthreads();
        #pragma unroll 4
        for (int dd = 0; dd < 64; ++dd) {
            float4 d0 = *(const float4*)&Ds[dd][8*tx];
            float4 d1 = *(const float4*)&Ds[dd][8*tx+4];
            float4 h0v = *(const float4*)&Hs[dd][8*ty];
            float4 h1v = *(const float4*)&Hs[dd][8*ty+4];
            float dv[8] = {d0.x,d0.y,d0.z,d0.w,d1.x,d1.y,d1.z,d1.w};
            float hv[8] = {h0v.x,h0v.y,h0v.z,h0v.w,h1v.x,h1v.y,h1v.z,h1v.w};
            #pragma unroll
            for (int a = 0; a < 8; ++a)
                #pragma unroll
                for (int c = 0; c < 8; ++c) acc[a][c] += dv[a] * hv[c];
        }
        __syncthreads();
    }
    #pragma unroll
    for (int a = 0; a < 8; ++a) {
        float* op = &out[((size_t)b*256 + n0 + 8*tx + a)*256 + t0 + 8*ty];
        *(float4*)(op)     = make_float4(acc[a][0], acc[a][1], acc[a][2], acc[a][3]);
        *(float4*)(op + 4) = make_float4(acc[a][4], acc[a][5], acc[a][6], acc[a][7]);
    }
}

// ---------------------------------------------------------------------------
extern "C" void kernel_launch(void* const* d_in, const int* in_sizes, int n_in,
                              void* d_out, int out_size, void* d_ws, size_t ws_size,
                              hipStream_t stream) {
    const float* y     = (const float*)d_in[0];
    const float* A     = (const float*)d_in[1];
    const float* D     = (const float*)d_in[2];
    const float* F     = (const float*)d_in[3];
    const float* lam1  = (const float*)d_in[4];
    const float* lam2  = (const float*)d_in[5];
    const float* alpha = (const float*)d_in[6];
    const float* h0    = (const float*)d_in[7];
    const float* U     = (const float*)d_in[8];
    float* out = (float*)d_out;
    float* ws  = (float*)d_ws;

    // ws layout (element offsets, fp32 unless noted) — verified to fit in R2
    const size_t oZ  = 0;           // 16.7M
    const size_t oH  = 16777216;    // 16.7M
    const size_t oWt = 33554432;
    const size_t oSt = 33619968;
    const size_t oPt = 33685504;
    const size_t oFD = 33751040;
    const size_t oG  = 33816576;
    const size_t oGD = 33882112;
    const size_t oAD = 33947648;
    const size_t oSh = 33964032;   // u32 packed half2
    const size_t oPh = 33996800;   // u32 packed half2

    float* Z  = ws + oZ;  float* H  = ws + oH;
    float* Wt = ws + oWt; float* St = ws + oSt; float* Pt = ws + oPt;
    float* FD = ws + oFD; float* G  = ws + oG;  float* GD = ws + oGD;
    float* AD = ws + oAD;
    u32* Sth = (u32*)(ws + oSh);
    u32* Pth = (u32*)(ws + oPh);

    prep1<<<576, 256, 0, stream>>>(A, D, F, lam2, FD, G, AD);
    prep2<<<768, 256, 0, stream>>>(A, D, alpha, FD, G, AD, Pt, GD, Wt);
    prep3<<<256, 256, 0, stream>>>(D, GD, alpha, St);
    prep4<<<256, 256, 0, stream>>>(St, Pt, Sth, Pth);
    {
        dim3 g(256, 4);
        zgemm<<<g, 256, 0, stream>>>(y, Wt, Z);
    }
    scan3<<<256, 1024, 0, stream>>>(Sth, Pth, Z, h0, U, lam1, lam2, alpha, H);
    {
        dim3 g(256, 4);
        ogemm<<<g, 256, 0, stream>>>(D, H, out);
    }
}